// Round 11
// baseline (74.837 us; speedup 1.0000x reference)
//
#include <hip/hip_runtime.h>

// Fused LSTM-heads + 4-layer MLP on the MATRIX pipe.
// 256-thread block = 4 independent wave-slices; each wave owns 64 rows + a
// 8.7KB LDS region. NEW vs r10: input rows are loaded COALESCED (lane l takes
// float2-pair p = l + 64*i of the wave's contiguous span) and transposed
// through LDS (stride-34 rows) so no VMEM instruction splits across sectors.
// Spill uses lane-local K-permuted b64 pairing; B-fragments pre-packed to the
// induced position->k map. relu via v_pk_max_f16 after packing (exact).
// Epilogue: f32 staging in LDS (9-pad), barrier, block-coalesced store.

#define BLK  256
#define WPB  4
#define KSEQ 11
#define WSTR 2176   // per-wave LDS region in u32 (64 rows * 34 u32 input layout)

typedef _Float16 h2   __attribute__((ext_vector_type(2)));
typedef _Float16 h8   __attribute__((ext_vector_type(8)));
typedef float    f4   __attribute__((ext_vector_type(4)));
typedef unsigned u16v __attribute__((ext_vector_type(16)));

#define N_FRAG_U32 6144   // 24 tiles * 64 lanes * 4 u32 (f16 pairs)
#define N_BIAS     768    // 12 bias-tiles * 64 lanes (f32 bits)
#define N_LSTM     288    // 12 * 24 floats (W_ih 16 + folded bias 8 per k)

__device__ __align__(16) float    g_lstm[N_LSTM];
__device__ __align__(16) unsigned g_frag[N_FRAG_U32];
__device__ __align__(16) unsigned g_bias[N_BIAS];

__device__ __forceinline__ h2 pk(float a, float b) {
    auto r = __builtin_amdgcn_cvt_pkrtz(a, b);
    union { decltype(r) f; h2 h; } c; c.f = r; return c.h;
}
__device__ __forceinline__ unsigned as_u32(h2 h) {
    union { h2 h; unsigned u; } c; c.h = h; return c.u;
}
__device__ __forceinline__ float uf(unsigned u) {
    union { unsigned u; float f; } c; c.u = u; return c.f;
}
__device__ __forceinline__ unsigned pkrelu(float a, float b) {   // pack then v_pk_max_f16
    h2 p = pk(a, b);
    h2 z = {(_Float16)0.0f, (_Float16)0.0f};
    h2 r = __builtin_elementwise_max(p, z);
    return as_u32(r);
}
__device__ __forceinline__ float fast_exp(float x) {
#if __has_builtin(__builtin_amdgcn_exp2f)
    return __builtin_amdgcn_exp2f(x * 1.44269504088896340736f);
#else
    return __expf(x);
#endif
}
__device__ __forceinline__ float fast_rcp(float x) {
#if __has_builtin(__builtin_amdgcn_rcpf)
    return __builtin_amdgcn_rcpf(x);
#else
    return 1.0f / x;
#endif
}
__device__ __forceinline__ float sig1(float x)  { return fast_rcp(1.0f + fast_exp(-x)); }
__device__ __forceinline__ float tanh1(float x) {
    float e = fast_exp(2.0f * x);
    return 1.0f - 2.0f * fast_rcp(e + 1.0f);
}

// scalar-pipe load of 48 u32 (LSTM params for a k-pair); waitcnt fused in-block
__device__ __forceinline__ void sload3(const unsigned* p, u16v& c0, u16v& c1, u16v& c2) {
    asm volatile("s_load_dwordx16 %0, %3, 0x0\n\t"
                 "s_load_dwordx16 %1, %3, 0x40\n\t"
                 "s_load_dwordx16 %2, %3, 0x80\n\t"
                 "s_waitcnt lgkmcnt(0)"
                 : "=&s"(c0), "=&s"(c1), "=&s"(c2) : "s"(p));
}
__device__ __forceinline__ unsigned pick48(const u16v& c0, const u16v& c1, const u16v& c2, int j) {
    return j < 16 ? c0[j] : (j < 32 ? c1[j - 16] : c2[j - 32]);
}

__device__ __forceinline__ void lstm_one(const u16v& c0, const u16v& c1, const u16v& c2, int base,
                                         float2 x, h2& outp)
{
    float w0  = uf(pick48(c0, c1, c2, base + 0)),  w1  = uf(pick48(c0, c1, c2, base + 1));
    float w2  = uf(pick48(c0, c1, c2, base + 2)),  w3  = uf(pick48(c0, c1, c2, base + 3));
    float w8  = uf(pick48(c0, c1, c2, base + 8)),  w9  = uf(pick48(c0, c1, c2, base + 9));
    float w10 = uf(pick48(c0, c1, c2, base + 10)), w11 = uf(pick48(c0, c1, c2, base + 11));
    float w12 = uf(pick48(c0, c1, c2, base + 12)), w13 = uf(pick48(c0, c1, c2, base + 13));
    float w14 = uf(pick48(c0, c1, c2, base + 14)), w15 = uf(pick48(c0, c1, c2, base + 15));
    float B0  = uf(pick48(c0, c1, c2, base + 16)), B1v = uf(pick48(c0, c1, c2, base + 17));
    float B4  = uf(pick48(c0, c1, c2, base + 20)), B5  = uf(pick48(c0, c1, c2, base + 21));
    float B6  = uf(pick48(c0, c1, c2, base + 22)), B7  = uf(pick48(c0, c1, c2, base + 23));

    float x0 = x.x, x1 = x.y;
    float gi0 = B0  + x0 * w0  + x1 * w1;
    float gi1 = B1v + x0 * w2  + x1 * w3;
    float gg0 = B4  + x0 * w8  + x1 * w9;
    float gg1 = B5  + x0 * w10 + x1 * w11;
    float go0 = B6  + x0 * w12 + x1 * w13;
    float go1 = B7  + x0 * w14 + x1 * w15;
    float cc0 = sig1(gi0) * tanh1(gg0);
    float cc1 = sig1(gi1) * tanh1(gg1);
    outp = pk(sig1(go0) * tanh1(cc0), sig1(go1) * tanh1(cc1));
}

// ---- prep: pack B-fragments, bias tiles, LSTM params ----
// tile ids: L1: 0..7 = ks*4+nt | L2: 8..15 | L3: 16..21 = 16+ks*3+nt | L4: 22..23
// Position->k map (u32 position p within a 32-position activation row):
//   L1 input (stage0, sequential): position p holds k-pair (2p, 2p+1)
//   L2/L3/L4 input (b64 spill):    p even -> (p/2, 16+p/2), p odd -> (32+p/2, 48+p/2)
// B element (lane,j) reads position p = ks*16 + (lane>>4)*4 + j.
__global__ void prep_weights(const float* __restrict__ W_ih, const float* __restrict__ b_ih,
                             const float* __restrict__ b_hh,
                             const float* __restrict__ W1, const float* __restrict__ b1,
                             const float* __restrict__ W2, const float* __restrict__ b2,
                             const float* __restrict__ W3, const float* __restrict__ b3,
                             const float* __restrict__ W4, const float* __restrict__ b4)
{
    const int gid = blockIdx.x * blockDim.x + threadIdx.x;
    const int gs  = gridDim.x * blockDim.x;

    for (int i = gid; i < N_FRAG_U32; i += gs) {
        int t = i >> 8, rlo = i & 255;
        int lane = rlo >> 2, j = rlo & 3;
        const float* W; int N, K, ld, ks, nt;
        if (t < 8)       { W = W1; N = 51; K = 34; ld = 34; ks = t >> 2;     nt = t & 3; }
        else if (t < 16) { W = W2; N = 51; K = 51; ld = 51; ks = (t-8) >> 2; nt = (t-8) & 3; }
        else if (t < 22) { W = W3; N = 34; K = 51; ld = 51; ks = (t-16) / 3; nt = (t-16) % 3; }
        else             { W = W4; N = 5;  K = 34; ld = 34; ks = t - 22;     nt = 0; }
        int n = nt * 16 + (lane & 15);
        int p = ks * 16 + (lane >> 4) * 4 + j;
        int k_lo, k_hi;
        if (t < 8) { k_lo = 2 * p;                              k_hi = k_lo + 1;  }
        else       { k_lo = (p & 1) ? 32 + (p >> 1) : (p >> 1); k_hi = k_lo + 16; }
        float a = (n < N && k_lo < K) ? W[n * ld + k_lo] : 0.f;
        float b = (n < N && k_hi < K) ? W[n * ld + k_hi] : 0.f;
        g_frag[i] = as_u32(pk(a, b));
    }
    for (int i = gid; i < N_BIAS; i += gs) {
        int bt = i >> 6, lane = i & 63;
        const float* bv; int N, nt;
        if (bt < 4)       { bv = b1; N = 51; nt = bt; }
        else if (bt < 8)  { bv = b2; N = 51; nt = bt - 4; }
        else if (bt < 11) { bv = b3; N = 34; nt = bt - 8; }
        else              { bv = b4; N = 5;  nt = 0; }
        int col = nt * 16 + (lane & 15);
        g_bias[i] = __float_as_uint(col < N ? bv[col] : 0.f);
    }
    for (int i = gid; i < N_LSTM; i += gs) {
        int k = i / 24, cc = i - k * 24;
        float v = 0.f;
        if (k < KSEQ) v = (cc < 16) ? W_ih[k * 16 + cc]
                                    : b_ih[k * 8 + (cc - 16)] + b_hh[k * 8 + (cc - 16)];
        g_lstm[i] = v;
    }
}

// ---- main kernel helpers ----
__device__ __forceinline__ h8 load_frag(int tile, int l) {
    union { uint4 u; h8 h; } u;
    u.u = *(const uint4*)&g_frag[tile * 256 + l * 4];
    return u.h;
}

__device__ __forceinline__ void read_afrags(h8 (&a)[4][2], const unsigned* my, int l)
{
    const int c = l & 15, g = l >> 4;
    const int mrd = (c & 7) << 2;                        // swizzle mask, row = c
    #pragma unroll
    for (int mt = 0; mt < 4; ++mt)
      #pragma unroll
      for (int ks = 0; ks < 2; ++ks) {
        int idx = (mt * 16 + c) * 32 + ((ks * 16 + g * 4) ^ mrd);
        union { uint4 u; h8 h; } u;
        u.u = *(const uint4*)&my[idx];
        a[mt][ks] = u.h;
      }
}

template<int NT, int TBASE, int BBASE>
__device__ __forceinline__ void layer_mfma(const h8 (&a)[4][2], f4 (&acc)[4][4],
                                           const float (&bs)[12], int l)
{
    #pragma unroll
    for (int mt = 0; mt < 4; ++mt)
      #pragma unroll
      for (int nt = 0; nt < NT; ++nt) {
        float b = bs[BBASE + nt];                        // bias rides in C
        acc[mt][nt] = f4{b, b, b, b};
      }
    #pragma unroll
    for (int ks = 0; ks < 2; ++ks)
      #pragma unroll
      for (int nt = 0; nt < NT; ++nt) {
        h8 bf = load_frag(TBASE + ks * NT + nt, l);
        #pragma unroll
        for (int mt = 0; mt < 4; ++mt)
          acc[mt][nt] = __builtin_amdgcn_mfma_f32_16x16x32_f16(a[mt][ks], bf, acc[mt][nt], 0, 0, 0);
      }
}

// pack + v_pk_max_f16 relu; ONE ds_write_b64 per (mt,r):
// position 2c holds cols (c, 16+c), position 2c+1 holds cols (32+c, 48+c).
template<int NT>
__device__ __forceinline__ void spill_act(const f4 (&acc)[4][4], unsigned* my, int l)
{
    const int g = l >> 4, c = l & 15;
    #pragma unroll
    for (int mt = 0; mt < 4; ++mt)
      #pragma unroll
      for (int r = 0; r < 4; ++r) {
        const int row  = mt * 16 + g * 4 + r;
        const int rowm = (row & 7) << 2;
        uint2 q;
        q.x = pkrelu(acc[mt][0][r], acc[mt][1][r]);
        float d3 = (NT >= 4) ? acc[mt][3][r] : 0.f;
        q.y = pkrelu(acc[mt][2][r], d3);
        *(uint2*)&my[row * 32 + ((2 * c) ^ rowm)] = q;
      }
}

__global__ __launch_bounds__(BLK, 4)
void fused_rnn_mlp(const float* __restrict__ in, float* __restrict__ out, int nrows)
{
    __shared__ unsigned act[WPB * WSTR];                 // 8.7 KB per wave-slice
    const int tid = threadIdx.x;
    const int w = tid >> 6, l = tid & 63;
    unsigned* my = &act[w * WSTR];
    const long long rb = (long long)blockIdx.x * BLK;
    if (rb + BLK > nrows) return;
    const long long rw = rb + w * 64;

    // bias tiles (12 coalesced dwords)
    float bs[12];
    #pragma unroll
    for (int i = 0; i < 12; ++i) bs[i] = uf(g_bias[i * 64 + l]);

    // ---- COALESCED input load + LDS transpose ----
    // lane l takes float2-pair p = l + 64*i of the wave's contiguous span
    // (64 rows x 17 pairs = 1088 pairs); writes to row-major stride-34 layout.
    {
        const float2* src = (const float2*)(in + rw * 34);
        float* myf = (float*)my;
        #pragma unroll
        for (int i = 0; i < 17; ++i) {
            unsigned p   = (unsigned)(l + 64 * i);
            float2   v   = src[p];
            unsigned row = (p * 123362u) >> 21;          // p / 17, exact for p < 2^20
            unsigned q   = p - row * 17u;
            *(float2*)&myf[row * 34 + 2 * q] = v;
        }
    }
    asm volatile("s_waitcnt lgkmcnt(0)" ::: "memory");
    __builtin_amdgcn_sched_barrier(0);

    // read own row back (17 x b64, ~4-way bank aliasing, 8B-aligned)
    float2 x[17];
    {
        const float* myf = (const float*)my;
        #pragma unroll
        for (int j = 0; j < 17; ++j) x[j] = *(const float2*)&myf[l * 34 + 2 * j];
    }
    asm volatile("s_waitcnt lgkmcnt(0)" ::: "memory");
    __builtin_amdgcn_sched_barrier(0);

    // LSTM heads (scalar-pipe params) -> 11 h-pairs + 6 passthrough pairs
    unsigned cp[32];
    #pragma unroll
    for (int kp = 0; kp < 6; ++kp) {
        u16v c0, c1, c2;
        sload3((const unsigned*)&g_lstm[kp * 48], c0, c1, c2);
        h2 h;
        lstm_one(c0, c1, c2, 0, x[2 * kp], h);
        cp[2 * kp] = as_u32(h);
        if (kp < 5) {
            lstm_one(c0, c1, c2, 24, x[2 * kp + 1], h);
            cp[2 * kp + 1] = as_u32(h);
        }
    }
    #pragma unroll
    for (int t = 0; t < 6; ++t) cp[11 + t] = as_u32(pk(x[11 + t].x, x[11 + t].y));
    #pragma unroll
    for (int t = 17; t < 32; ++t) cp[t] = 0u;            // zero K-tail (NaN-safe)

    // stage0: write own full row (row = l), sequential pairs, swizzled
    {
        const int m = (l & 7) << 2;
        #pragma unroll
        for (int ch = 0; ch < 8; ++ch) {
            uint4 q = make_uint4(cp[4*ch], cp[4*ch+1], cp[4*ch+2], cp[4*ch+3]);
            *(uint4*)&my[l * 32 + ((4 * ch) ^ m)] = q;
        }
    }

    h8 a[4][2];
    f4 acc[4][4];

    read_afrags(a, my, l);
    layer_mfma<4, 0, 0>(a, acc, bs, l);      // L1: 34 -> 51
    spill_act<4>(acc, my, l);

    read_afrags(a, my, l);
    layer_mfma<4, 8, 4>(a, acc, bs, l);      // L2: 51 -> 51
    spill_act<4>(acc, my, l);

    read_afrags(a, my, l);
    layer_mfma<3, 16, 8>(a, acc, bs, l);     // L3: 51 -> 34
    spill_act<3>(acc, my, l);

    read_afrags(a, my, l);
    layer_mfma<1, 22, 11>(a, acc, bs, l);    // L4: 34 -> 5

    // sigmoid -> stage f32 into own (now dead) act region, 9-padded
    {
        const int c = l & 15, g = l >> 4;
        float* po = (float*)my;
        if (c < 5) {
            #pragma unroll
            for (int mt = 0; mt < 4; ++mt)
              #pragma unroll
              for (int r = 0; r < 4; ++r)
                po[(mt * 16 + g * 4 + r) * 9 + c] = sig1(acc[mt][0][r]);
        }
    }
    __syncthreads();

    // block-wide coalesced store: 1280 contiguous floats
    const long long ob = rb * 5;
    const float* pact = (const float*)act;
    #pragma unroll
    for (int it = 0; it < 5; ++it) {
        int F   = it * BLK + tid;
        int row = (F * 52429) >> 18;                     // F / 5, exact for F < 2^15
        int cc  = F - row * 5;
        out[ob + F] = pact[(row >> 6) * WSTR + (row & 63) * 9 + cc];
    }
}

extern "C" void kernel_launch(void* const* d_in, const int* in_sizes, int n_in,
                              void* d_out, int out_size, void* d_ws, size_t ws_size,
                              hipStream_t stream)
{
    const float* input = (const float*)d_in[0];
    const float* W_ih  = (const float*)d_in[1];
    const float* b_ih  = (const float*)d_in[2];
    const float* b_hh  = (const float*)d_in[3];
    const float* W1    = (const float*)d_in[4];
    const float* b1    = (const float*)d_in[5];
    const float* W2    = (const float*)d_in[6];
    const float* b2    = (const float*)d_in[7];
    const float* W3    = (const float*)d_in[8];
    const float* b3    = (const float*)d_in[9];
    const float* W4    = (const float*)d_in[10];
    const float* b4    = (const float*)d_in[11];
    float* out = (float*)d_out;

    int nrows = in_sizes[0] / 34;
    int grid  = nrows / BLK;

    hipLaunchKernelGGL(prep_weights, dim3(8), dim3(256), 0, stream,
                       W_ih, b_ih, b_hh, W1, b1, W2, b2, W3, b3, W4, b4);
    hipLaunchKernelGGL(fused_rnn_mlp, dim3(grid), dim3(BLK), 0, stream,
                       input, out, nrows);
}

// Round 12
// 65.691 us; speedup vs baseline: 1.1392x; 1.1392x over previous
//
#include <hip/hip_runtime.h>

// Fused LSTM-heads + 4-layer MLP on the MATRIX pipe.
// 256-thread block = 4 independent wave-slices; each wave owns 64 rows + an
// 8.5KB LDS region. Input rows loaded COALESCED (lane l takes float2-pair
// p = l + 64*i of the wave's contiguous span) and transposed through LDS
// (stride-34 rows, 4-way readback aliasing). vs r11: launch_bounds(256,3)
// (un-starve the register allocator -> no scratch spill) and NO asm fences
// (compiler tracks same-wave LDS RAW, as proven by the spill->read path).
// Spill uses lane-local K-permuted b64 pairing; B-fragments pre-packed to the
// induced position->k map. relu via v_pk_max_f16 after packing (exact).
// Epilogue: f32 staging in LDS (9-pad), barrier, block-coalesced store.

#define BLK  256
#define WPB  4
#define KSEQ 11
#define WSTR 2176   // per-wave LDS region in u32 (64 rows * 34 u32 input layout)

typedef _Float16 h2   __attribute__((ext_vector_type(2)));
typedef _Float16 h8   __attribute__((ext_vector_type(8)));
typedef float    f4   __attribute__((ext_vector_type(4)));
typedef unsigned u16v __attribute__((ext_vector_type(16)));

#define N_FRAG_U32 6144   // 24 tiles * 64 lanes * 4 u32 (f16 pairs)
#define N_BIAS     768    // 12 bias-tiles * 64 lanes (f32 bits)
#define N_LSTM     288    // 12 * 24 floats (W_ih 16 + folded bias 8 per k)

__device__ __align__(16) float    g_lstm[N_LSTM];
__device__ __align__(16) unsigned g_frag[N_FRAG_U32];
__device__ __align__(16) unsigned g_bias[N_BIAS];

__device__ __forceinline__ h2 pk(float a, float b) {
    auto r = __builtin_amdgcn_cvt_pkrtz(a, b);
    union { decltype(r) f; h2 h; } c; c.f = r; return c.h;
}
__device__ __forceinline__ unsigned as_u32(h2 h) {
    union { h2 h; unsigned u; } c; c.h = h; return c.u;
}
__device__ __forceinline__ float uf(unsigned u) {
    union { unsigned u; float f; } c; c.u = u; return c.f;
}
__device__ __forceinline__ unsigned pkrelu(float a, float b) {   // pack then v_pk_max_f16
    h2 p = pk(a, b);
    h2 z = {(_Float16)0.0f, (_Float16)0.0f};
    h2 r = __builtin_elementwise_max(p, z);
    return as_u32(r);
}
__device__ __forceinline__ float fast_exp(float x) {
#if __has_builtin(__builtin_amdgcn_exp2f)
    return __builtin_amdgcn_exp2f(x * 1.44269504088896340736f);
#else
    return __expf(x);
#endif
}
__device__ __forceinline__ float fast_rcp(float x) {
#if __has_builtin(__builtin_amdgcn_rcpf)
    return __builtin_amdgcn_rcpf(x);
#else
    return 1.0f / x;
#endif
}
__device__ __forceinline__ float sig1(float x)  { return fast_rcp(1.0f + fast_exp(-x)); }
__device__ __forceinline__ float tanh1(float x) {
    float e = fast_exp(2.0f * x);
    return 1.0f - 2.0f * fast_rcp(e + 1.0f);
}

// scalar-pipe load of 48 u32 (LSTM params for a k-pair); waitcnt fused in-block
__device__ __forceinline__ void sload3(const unsigned* p, u16v& c0, u16v& c1, u16v& c2) {
    asm volatile("s_load_dwordx16 %0, %3, 0x0\n\t"
                 "s_load_dwordx16 %1, %3, 0x40\n\t"
                 "s_load_dwordx16 %2, %3, 0x80\n\t"
                 "s_waitcnt lgkmcnt(0)"
                 : "=&s"(c0), "=&s"(c1), "=&s"(c2) : "s"(p));
}
__device__ __forceinline__ unsigned pick48(const u16v& c0, const u16v& c1, const u16v& c2, int j) {
    return j < 16 ? c0[j] : (j < 32 ? c1[j - 16] : c2[j - 32]);
}

__device__ __forceinline__ void lstm_one(const u16v& c0, const u16v& c1, const u16v& c2, int base,
                                         float2 x, h2& outp)
{
    float w0  = uf(pick48(c0, c1, c2, base + 0)),  w1  = uf(pick48(c0, c1, c2, base + 1));
    float w2  = uf(pick48(c0, c1, c2, base + 2)),  w3  = uf(pick48(c0, c1, c2, base + 3));
    float w8  = uf(pick48(c0, c1, c2, base + 8)),  w9  = uf(pick48(c0, c1, c2, base + 9));
    float w10 = uf(pick48(c0, c1, c2, base + 10)), w11 = uf(pick48(c0, c1, c2, base + 11));
    float w12 = uf(pick48(c0, c1, c2, base + 12)), w13 = uf(pick48(c0, c1, c2, base + 13));
    float w14 = uf(pick48(c0, c1, c2, base + 14)), w15 = uf(pick48(c0, c1, c2, base + 15));
    float B0  = uf(pick48(c0, c1, c2, base + 16)), B1v = uf(pick48(c0, c1, c2, base + 17));
    float B4  = uf(pick48(c0, c1, c2, base + 20)), B5  = uf(pick48(c0, c1, c2, base + 21));
    float B6  = uf(pick48(c0, c1, c2, base + 22)), B7  = uf(pick48(c0, c1, c2, base + 23));

    float x0 = x.x, x1 = x.y;
    float gi0 = B0  + x0 * w0  + x1 * w1;
    float gi1 = B1v + x0 * w2  + x1 * w3;
    float gg0 = B4  + x0 * w8  + x1 * w9;
    float gg1 = B5  + x0 * w10 + x1 * w11;
    float go0 = B6  + x0 * w12 + x1 * w13;
    float go1 = B7  + x0 * w14 + x1 * w15;
    float cc0 = sig1(gi0) * tanh1(gg0);
    float cc1 = sig1(gi1) * tanh1(gg1);
    outp = pk(sig1(go0) * tanh1(cc0), sig1(go1) * tanh1(cc1));
}

// ---- prep: pack B-fragments, bias tiles, LSTM params ----
// tile ids: L1: 0..7 = ks*4+nt | L2: 8..15 | L3: 16..21 = 16+ks*3+nt | L4: 22..23
// Position->k map (u32 position p within a 32-position activation row):
//   L1 input (stage0, sequential): position p holds k-pair (2p, 2p+1)
//   L2/L3/L4 input (b64 spill):    p even -> (p/2, 16+p/2), p odd -> (32+p/2, 48+p/2)
// B element (lane,j) reads position p = ks*16 + (lane>>4)*4 + j.
__global__ void prep_weights(const float* __restrict__ W_ih, const float* __restrict__ b_ih,
                             const float* __restrict__ b_hh,
                             const float* __restrict__ W1, const float* __restrict__ b1,
                             const float* __restrict__ W2, const float* __restrict__ b2,
                             const float* __restrict__ W3, const float* __restrict__ b3,
                             const float* __restrict__ W4, const float* __restrict__ b4)
{
    const int gid = blockIdx.x * blockDim.x + threadIdx.x;
    const int gs  = gridDim.x * blockDim.x;

    for (int i = gid; i < N_FRAG_U32; i += gs) {
        int t = i >> 8, rlo = i & 255;
        int lane = rlo >> 2, j = rlo & 3;
        const float* W; int N, K, ld, ks, nt;
        if (t < 8)       { W = W1; N = 51; K = 34; ld = 34; ks = t >> 2;     nt = t & 3; }
        else if (t < 16) { W = W2; N = 51; K = 51; ld = 51; ks = (t-8) >> 2; nt = (t-8) & 3; }
        else if (t < 22) { W = W3; N = 34; K = 51; ld = 51; ks = (t-16) / 3; nt = (t-16) % 3; }
        else             { W = W4; N = 5;  K = 34; ld = 34; ks = t - 22;     nt = 0; }
        int n = nt * 16 + (lane & 15);
        int p = ks * 16 + (lane >> 4) * 4 + j;
        int k_lo, k_hi;
        if (t < 8) { k_lo = 2 * p;                              k_hi = k_lo + 1;  }
        else       { k_lo = (p & 1) ? 32 + (p >> 1) : (p >> 1); k_hi = k_lo + 16; }
        float a = (n < N && k_lo < K) ? W[n * ld + k_lo] : 0.f;
        float b = (n < N && k_hi < K) ? W[n * ld + k_hi] : 0.f;
        g_frag[i] = as_u32(pk(a, b));
    }
    for (int i = gid; i < N_BIAS; i += gs) {
        int bt = i >> 6, lane = i & 63;
        const float* bv; int N, nt;
        if (bt < 4)       { bv = b1; N = 51; nt = bt; }
        else if (bt < 8)  { bv = b2; N = 51; nt = bt - 4; }
        else if (bt < 11) { bv = b3; N = 34; nt = bt - 8; }
        else              { bv = b4; N = 5;  nt = 0; }
        int col = nt * 16 + (lane & 15);
        g_bias[i] = __float_as_uint(col < N ? bv[col] : 0.f);
    }
    for (int i = gid; i < N_LSTM; i += gs) {
        int k = i / 24, cc = i - k * 24;
        float v = 0.f;
        if (k < KSEQ) v = (cc < 16) ? W_ih[k * 16 + cc]
                                    : b_ih[k * 8 + (cc - 16)] + b_hh[k * 8 + (cc - 16)];
        g_lstm[i] = v;
    }
}

// ---- main kernel helpers ----
__device__ __forceinline__ h8 load_frag(int tile, int l) {
    union { uint4 u; h8 h; } u;
    u.u = *(const uint4*)&g_frag[tile * 256 + l * 4];
    return u.h;
}

__device__ __forceinline__ void read_afrags(h8 (&a)[4][2], const unsigned* my, int l)
{
    const int c = l & 15, g = l >> 4;
    const int mrd = (c & 7) << 2;                        // swizzle mask, row = c
    #pragma unroll
    for (int mt = 0; mt < 4; ++mt)
      #pragma unroll
      for (int ks = 0; ks < 2; ++ks) {
        int idx = (mt * 16 + c) * 32 + ((ks * 16 + g * 4) ^ mrd);
        union { uint4 u; h8 h; } u;
        u.u = *(const uint4*)&my[idx];
        a[mt][ks] = u.h;
      }
}

template<int NT, int TBASE, int BBASE>
__device__ __forceinline__ void layer_mfma(const h8 (&a)[4][2], f4 (&acc)[4][4],
                                           const float (&bs)[12], int l)
{
    #pragma unroll
    for (int mt = 0; mt < 4; ++mt)
      #pragma unroll
      for (int nt = 0; nt < NT; ++nt) {
        float b = bs[BBASE + nt];                        // bias rides in C
        acc[mt][nt] = f4{b, b, b, b};
      }
    #pragma unroll
    for (int ks = 0; ks < 2; ++ks)
      #pragma unroll
      for (int nt = 0; nt < NT; ++nt) {
        h8 bf = load_frag(TBASE + ks * NT + nt, l);
        #pragma unroll
        for (int mt = 0; mt < 4; ++mt)
          acc[mt][nt] = __builtin_amdgcn_mfma_f32_16x16x32_f16(a[mt][ks], bf, acc[mt][nt], 0, 0, 0);
      }
}

// pack + v_pk_max_f16 relu; ONE ds_write_b64 per (mt,r):
// position 2c holds cols (c, 16+c), position 2c+1 holds cols (32+c, 48+c).
template<int NT>
__device__ __forceinline__ void spill_act(const f4 (&acc)[4][4], unsigned* my, int l)
{
    const int g = l >> 4, c = l & 15;
    #pragma unroll
    for (int mt = 0; mt < 4; ++mt)
      #pragma unroll
      for (int r = 0; r < 4; ++r) {
        const int row  = mt * 16 + g * 4 + r;
        const int rowm = (row & 7) << 2;
        uint2 q;
        q.x = pkrelu(acc[mt][0][r], acc[mt][1][r]);
        float d3 = (NT >= 4) ? acc[mt][3][r] : 0.f;
        q.y = pkrelu(acc[mt][2][r], d3);
        *(uint2*)&my[row * 32 + ((2 * c) ^ rowm)] = q;
      }
}

__global__ __launch_bounds__(BLK, 3)
void fused_rnn_mlp(const float* __restrict__ in, float* __restrict__ out, int nrows)
{
    __shared__ unsigned act[WPB * WSTR];                 // 8.5 KB per wave-slice
    const int tid = threadIdx.x;
    const int w = tid >> 6, l = tid & 63;
    unsigned* my = &act[w * WSTR];
    const long long rb = (long long)blockIdx.x * BLK;
    if (rb + BLK > nrows) return;
    const long long rw = rb + w * 64;

    // bias tiles (12 coalesced dwords)
    float bs[12];
    #pragma unroll
    for (int i = 0; i < 12; ++i) bs[i] = uf(g_bias[i * 64 + l]);

    // ---- COALESCED input load + LDS transpose (no explicit fences:
    // compiler tracks same-wave LDS RAW, as in the spill->read path) ----
    {
        const float2* src = (const float2*)(in + rw * 34);
        float* myf = (float*)my;
        #pragma unroll
        for (int i = 0; i < 17; ++i) {
            unsigned p   = (unsigned)(l + 64 * i);
            float2   v   = src[p];
            unsigned row = (p * 123362u) >> 21;          // p / 17, exact for p < 2^20
            unsigned q   = p - row * 17u;
            *(float2*)&myf[row * 34 + 2 * q] = v;
        }
    }

    // read own row back (17 x b64, 4-way bank aliasing, 8B-aligned)
    float2 x[17];
    {
        const float* myf = (const float*)my;
        #pragma unroll
        for (int j = 0; j < 17; ++j) x[j] = *(const float2*)&myf[l * 34 + 2 * j];
    }

    // LSTM heads (scalar-pipe params) -> 11 h-pairs + 6 passthrough pairs
    unsigned cp[32];
    #pragma unroll
    for (int kp = 0; kp < 6; ++kp) {
        u16v c0, c1, c2;
        sload3((const unsigned*)&g_lstm[kp * 48], c0, c1, c2);
        h2 h;
        lstm_one(c0, c1, c2, 0, x[2 * kp], h);
        cp[2 * kp] = as_u32(h);
        if (kp < 5) {
            lstm_one(c0, c1, c2, 24, x[2 * kp + 1], h);
            cp[2 * kp + 1] = as_u32(h);
        }
    }
    #pragma unroll
    for (int t = 0; t < 6; ++t) cp[11 + t] = as_u32(pk(x[11 + t].x, x[11 + t].y));
    #pragma unroll
    for (int t = 17; t < 32; ++t) cp[t] = 0u;            // zero K-tail (NaN-safe)

    // stage0: write own full row (row = l), sequential pairs, swizzled
    {
        const int m = (l & 7) << 2;
        #pragma unroll
        for (int ch = 0; ch < 8; ++ch) {
            uint4 q = make_uint4(cp[4*ch], cp[4*ch+1], cp[4*ch+2], cp[4*ch+3]);
            *(uint4*)&my[l * 32 + ((4 * ch) ^ m)] = q;
        }
    }

    h8 a[4][2];
    f4 acc[4][4];

    read_afrags(a, my, l);
    layer_mfma<4, 0, 0>(a, acc, bs, l);      // L1: 34 -> 51
    spill_act<4>(acc, my, l);

    read_afrags(a, my, l);
    layer_mfma<4, 8, 4>(a, acc, bs, l);      // L2: 51 -> 51
    spill_act<4>(acc, my, l);

    read_afrags(a, my, l);
    layer_mfma<3, 16, 8>(a, acc, bs, l);     // L3: 51 -> 34
    spill_act<3>(acc, my, l);

    read_afrags(a, my, l);
    layer_mfma<1, 22, 11>(a, acc, bs, l);    // L4: 34 -> 5

    // sigmoid -> stage f32 into own (now dead) act region, 9-padded
    {
        const int c = l & 15, g = l >> 4;
        float* po = (float*)my;
        if (c < 5) {
            #pragma unroll
            for (int mt = 0; mt < 4; ++mt)
              #pragma unroll
              for (int r = 0; r < 4; ++r)
                po[(mt * 16 + g * 4 + r) * 9 + c] = sig1(acc[mt][0][r]);
        }
    }
    __syncthreads();

    // block-wide coalesced store: 1280 contiguous floats
    const long long ob = rb * 5;
    const float* pact = (const float*)act;
    #pragma unroll
    for (int it = 0; it < 5; ++it) {
        int F   = it * BLK + tid;
        int row = (F * 52429) >> 18;                     // F / 5, exact for F < 2^15
        int cc  = F - row * 5;
        out[ob + F] = pact[(row >> 6) * WSTR + (row & 63) * 9 + cc];
    }
}

extern "C" void kernel_launch(void* const* d_in, const int* in_sizes, int n_in,
                              void* d_out, int out_size, void* d_ws, size_t ws_size,
                              hipStream_t stream)
{
    const float* input = (const float*)d_in[0];
    const float* W_ih  = (const float*)d_in[1];
    const float* b_ih  = (const float*)d_in[2];
    const float* b_hh  = (const float*)d_in[3];
    const float* W1    = (const float*)d_in[4];
    const float* b1    = (const float*)d_in[5];
    const float* W2    = (const float*)d_in[6];
    const float* b2    = (const float*)d_in[7];
    const float* W3    = (const float*)d_in[8];
    const float* b3    = (const float*)d_in[9];
    const float* W4    = (const float*)d_in[10];
    const float* b4    = (const float*)d_in[11];
    float* out = (float*)d_out;

    int nrows = in_sizes[0] / 34;
    int grid  = nrows / BLK;

    hipLaunchKernelGGL(prep_weights, dim3(8), dim3(256), 0, stream,
                       W_ih, b_ih, b_hh, W1, b1, W2, b2, W3, b3, W4, b4);
    hipLaunchKernelGGL(fused_rnn_mlp, dim3(grid), dim3(BLK), 0, stream,
                       input, out, nrows);
}

// Round 13
// 60.134 us; speedup vs baseline: 1.2445x; 1.0924x over previous
//
#include <hip/hip_runtime.h>

// Fused LSTM-heads + 4-layer MLP on the MATRIX pipe.  (r10 structure)
// 256-thread block = 4 independent wave-slices; each wave owns 64 rows + an
// 8KB LDS activation tile. Spill uses lane-local K-permuted pairing with
// ADJACENT positions (2c -> cols (c,16+c), 2c+1 -> cols (32+c,48+c)) so each
// (mt,r) is ONE ds_write_b64; L2/L3/L4 B-fragments pre-packed to the induced
// position->k map. relu via v_pk_max_f16 after packing (exact).
// r13: (a) LSTM gates use fused-rcp sig*tanh (one rcp per pair, -44 trans/lane)
//      (b) epilogue stages PRE-sigmoid f32; sigmoid applied in the block-wide
//          store loop (5 trans/thread, full lane utilization, no mask).

#define BLK  256
#define WPB  4
#define KSEQ 11

typedef _Float16 h2   __attribute__((ext_vector_type(2)));
typedef _Float16 h8   __attribute__((ext_vector_type(8)));
typedef float    f4   __attribute__((ext_vector_type(4)));
typedef unsigned u16v __attribute__((ext_vector_type(16)));

#define N_FRAG_U32 6144   // 24 tiles * 64 lanes * 4 u32 (f16 pairs)
#define N_BIAS     768    // 12 bias-tiles * 64 lanes (f32 bits)
#define N_LSTM     288    // 12 * 24 floats (W_ih 16 + folded bias 8 per k)

__device__ __align__(16) float    g_lstm[N_LSTM];
__device__ __align__(16) unsigned g_frag[N_FRAG_U32];
__device__ __align__(16) unsigned g_bias[N_BIAS];

__device__ __forceinline__ h2 pk(float a, float b) {
    auto r = __builtin_amdgcn_cvt_pkrtz(a, b);
    union { decltype(r) f; h2 h; } c; c.f = r; return c.h;
}
__device__ __forceinline__ unsigned as_u32(h2 h) {
    union { h2 h; unsigned u; } c; c.h = h; return c.u;
}
__device__ __forceinline__ float uf(unsigned u) {
    union { unsigned u; float f; } c; c.u = u; return c.f;
}
__device__ __forceinline__ unsigned pkrelu(float a, float b) {   // pack then v_pk_max_f16
    h2 p = pk(a, b);
    h2 z = {(_Float16)0.0f, (_Float16)0.0f};
    h2 r = __builtin_elementwise_max(p, z);
    return as_u32(r);
}
__device__ __forceinline__ float fast_exp(float x) {
#if __has_builtin(__builtin_amdgcn_exp2f)
    return __builtin_amdgcn_exp2f(x * 1.44269504088896340736f);
#else
    return __expf(x);
#endif
}
__device__ __forceinline__ float fast_rcp(float x) {
#if __has_builtin(__builtin_amdgcn_rcpf)
    return __builtin_amdgcn_rcpf(x);
#else
    return 1.0f / x;
#endif
}
__device__ __forceinline__ float sig1(float x)  { return fast_rcp(1.0f + fast_exp(-x)); }

// sig(a) * tanh(b) with a single rcp:
// = (e^{2b} - 1) / [ (1 + e^{-a}) * (e^{2b} + 1) ]
__device__ __forceinline__ float sigtanh(float a, float b) {
    float ea = fast_exp(-a);
    float eb = fast_exp(2.0f * b);
    return (eb - 1.0f) * fast_rcp((1.0f + ea) * (eb + 1.0f));
}

// scalar-pipe load of 48 u32 (LSTM params for a k-pair); waitcnt fused in-block
__device__ __forceinline__ void sload3(const unsigned* p, u16v& c0, u16v& c1, u16v& c2) {
    asm volatile("s_load_dwordx16 %0, %3, 0x0\n\t"
                 "s_load_dwordx16 %1, %3, 0x40\n\t"
                 "s_load_dwordx16 %2, %3, 0x80\n\t"
                 "s_waitcnt lgkmcnt(0)"
                 : "=&s"(c0), "=&s"(c1), "=&s"(c2) : "s"(p));
}
__device__ __forceinline__ unsigned pick48(const u16v& c0, const u16v& c1, const u16v& c2, int j) {
    return j < 16 ? c0[j] : (j < 32 ? c1[j - 16] : c2[j - 32]);
}

__device__ __forceinline__ void lstm_one(const u16v& c0, const u16v& c1, const u16v& c2, int base,
                                         float2 x, h2& outp)
{
    float w0  = uf(pick48(c0, c1, c2, base + 0)),  w1  = uf(pick48(c0, c1, c2, base + 1));
    float w2  = uf(pick48(c0, c1, c2, base + 2)),  w3  = uf(pick48(c0, c1, c2, base + 3));
    float w8  = uf(pick48(c0, c1, c2, base + 8)),  w9  = uf(pick48(c0, c1, c2, base + 9));
    float w10 = uf(pick48(c0, c1, c2, base + 10)), w11 = uf(pick48(c0, c1, c2, base + 11));
    float w12 = uf(pick48(c0, c1, c2, base + 12)), w13 = uf(pick48(c0, c1, c2, base + 13));
    float w14 = uf(pick48(c0, c1, c2, base + 14)), w15 = uf(pick48(c0, c1, c2, base + 15));
    float B0  = uf(pick48(c0, c1, c2, base + 16)), B1v = uf(pick48(c0, c1, c2, base + 17));
    float B4  = uf(pick48(c0, c1, c2, base + 20)), B5  = uf(pick48(c0, c1, c2, base + 21));
    float B6  = uf(pick48(c0, c1, c2, base + 22)), B7  = uf(pick48(c0, c1, c2, base + 23));

    float x0 = x.x, x1 = x.y;
    float gi0 = B0  + x0 * w0  + x1 * w1;
    float gi1 = B1v + x0 * w2  + x1 * w3;
    float gg0 = B4  + x0 * w8  + x1 * w9;
    float gg1 = B5  + x0 * w10 + x1 * w11;
    float go0 = B6  + x0 * w12 + x1 * w13;
    float go1 = B7  + x0 * w14 + x1 * w15;
    float cc0 = sigtanh(gi0, gg0);
    float cc1 = sigtanh(gi1, gg1);
    float h0  = sigtanh(go0, cc0);
    float h1  = sigtanh(go1, cc1);
    outp = pk(h0, h1);
}

// ---- prep: pack B-fragments, bias tiles, LSTM params ----
// tile ids: L1: 0..7 = ks*4+nt | L2: 8..15 | L3: 16..21 = 16+ks*3+nt | L4: 22..23
// Position->k map (u32 position p within a 32-position activation row):
//   L1 input (stage0, sequential): position p holds k-pair (2p, 2p+1)
//   L2/L3/L4 input (b64 spill):    p even -> (p/2, 16+p/2), p odd -> (32+p/2, 48+p/2)
// B element (lane,j) reads position p = ks*16 + (lane>>4)*4 + j.
__global__ void prep_weights(const float* __restrict__ W_ih, const float* __restrict__ b_ih,
                             const float* __restrict__ b_hh,
                             const float* __restrict__ W1, const float* __restrict__ b1,
                             const float* __restrict__ W2, const float* __restrict__ b2,
                             const float* __restrict__ W3, const float* __restrict__ b3,
                             const float* __restrict__ W4, const float* __restrict__ b4)
{
    const int gid = blockIdx.x * blockDim.x + threadIdx.x;
    const int gs  = gridDim.x * blockDim.x;

    for (int i = gid; i < N_FRAG_U32; i += gs) {
        int t = i >> 8, rlo = i & 255;
        int lane = rlo >> 2, j = rlo & 3;
        const float* W; int N, K, ld, ks, nt;
        if (t < 8)       { W = W1; N = 51; K = 34; ld = 34; ks = t >> 2;     nt = t & 3; }
        else if (t < 16) { W = W2; N = 51; K = 51; ld = 51; ks = (t-8) >> 2; nt = (t-8) & 3; }
        else if (t < 22) { W = W3; N = 34; K = 51; ld = 51; ks = (t-16) / 3; nt = (t-16) % 3; }
        else             { W = W4; N = 5;  K = 34; ld = 34; ks = t - 22;     nt = 0; }
        int n = nt * 16 + (lane & 15);
        int p = ks * 16 + (lane >> 4) * 4 + j;
        int k_lo, k_hi;
        if (t < 8) { k_lo = 2 * p;                              k_hi = k_lo + 1;  }
        else       { k_lo = (p & 1) ? 32 + (p >> 1) : (p >> 1); k_hi = k_lo + 16; }
        float a = (n < N && k_lo < K) ? W[n * ld + k_lo] : 0.f;
        float b = (n < N && k_hi < K) ? W[n * ld + k_hi] : 0.f;
        g_frag[i] = as_u32(pk(a, b));
    }
    for (int i = gid; i < N_BIAS; i += gs) {
        int bt = i >> 6, lane = i & 63;
        const float* bv; int N, nt;
        if (bt < 4)       { bv = b1; N = 51; nt = bt; }
        else if (bt < 8)  { bv = b2; N = 51; nt = bt - 4; }
        else if (bt < 11) { bv = b3; N = 34; nt = bt - 8; }
        else              { bv = b4; N = 5;  nt = 0; }
        int col = nt * 16 + (lane & 15);
        g_bias[i] = __float_as_uint(col < N ? bv[col] : 0.f);
    }
    for (int i = gid; i < N_LSTM; i += gs) {
        int k = i / 24, cc = i - k * 24;
        float v = 0.f;
        if (k < KSEQ) v = (cc < 16) ? W_ih[k * 16 + cc]
                                    : b_ih[k * 8 + (cc - 16)] + b_hh[k * 8 + (cc - 16)];
        g_lstm[i] = v;
    }
}

// ---- main kernel helpers ----
__device__ __forceinline__ h8 load_frag(int tile, int l) {
    union { uint4 u; h8 h; } u;
    u.u = *(const uint4*)&g_frag[tile * 256 + l * 4];
    return u.h;
}

__device__ __forceinline__ void read_afrags(h8 (&a)[4][2], const unsigned* my, int l)
{
    const int c = l & 15, g = l >> 4;
    const int mrd = (c & 7) << 2;                        // swizzle mask, row = c
    #pragma unroll
    for (int mt = 0; mt < 4; ++mt)
      #pragma unroll
      for (int ks = 0; ks < 2; ++ks) {
        int idx = (mt * 16 + c) * 32 + ((ks * 16 + g * 4) ^ mrd);
        union { uint4 u; h8 h; } u;
        u.u = *(const uint4*)&my[idx];
        a[mt][ks] = u.h;
      }
}

template<int NT, int TBASE, int BBASE>
__device__ __forceinline__ void layer_mfma(const h8 (&a)[4][2], f4 (&acc)[4][4],
                                           const float (&bs)[12], int l)
{
    #pragma unroll
    for (int mt = 0; mt < 4; ++mt)
      #pragma unroll
      for (int nt = 0; nt < NT; ++nt) {
        float b = bs[BBASE + nt];                        // bias rides in C
        acc[mt][nt] = f4{b, b, b, b};
      }
    #pragma unroll
    for (int ks = 0; ks < 2; ++ks)
      #pragma unroll
      for (int nt = 0; nt < NT; ++nt) {
        h8 bf = load_frag(TBASE + ks * NT + nt, l);
        #pragma unroll
        for (int mt = 0; mt < 4; ++mt)
          acc[mt][nt] = __builtin_amdgcn_mfma_f32_16x16x32_f16(a[mt][ks], bf, acc[mt][nt], 0, 0, 0);
      }
}

// pack + v_pk_max_f16 relu; ONE ds_write_b64 per (mt,r):
// position 2c holds cols (c, 16+c), position 2c+1 holds cols (32+c, 48+c).
// Swizzle mask has bits >=2 only, so (2c)^rowm stays 8B-aligned.
template<int NT>
__device__ __forceinline__ void spill_act(const f4 (&acc)[4][4], unsigned* my, int l)
{
    const int g = l >> 4, c = l & 15;
    #pragma unroll
    for (int mt = 0; mt < 4; ++mt)
      #pragma unroll
      for (int r = 0; r < 4; ++r) {
        const int row  = mt * 16 + g * 4 + r;
        const int rowm = (row & 7) << 2;
        uint2 q;
        q.x = pkrelu(acc[mt][0][r], acc[mt][1][r]);
        float d3 = (NT >= 4) ? acc[mt][3][r] : 0.f;
        q.y = pkrelu(acc[mt][2][r], d3);
        *(uint2*)&my[row * 32 + ((2 * c) ^ rowm)] = q;
      }
}

__global__ __launch_bounds__(BLK, 3)
void fused_rnn_mlp(const float* __restrict__ in, float* __restrict__ out, int nrows)
{
    __shared__ unsigned act[WPB * 2048];                 // 8 KB per wave-slice
    const int tid = threadIdx.x;
    const int w = tid >> 6, l = tid & 63;
    unsigned* my = &act[w * 2048];
    const long long rb = (long long)blockIdx.x * BLK;
    if (rb + BLK > nrows) return;
    const long long rw = rb + w * 64;

    // bias tiles (12 coalesced dwords)
    float bs[12];
    #pragma unroll
    for (int i = 0; i < 12; ++i) bs[i] = uf(g_bias[i * 64 + l]);

    // own row (8B-aligned, 136B stride)
    float2 x[17];
    {
        const float2* rp = (const float2*)(in + (rw + l) * 34);
        #pragma unroll
        for (int i = 0; i < 17; ++i) x[i] = rp[i];
    }

    // LSTM heads (scalar-pipe params) -> 11 h-pairs + 6 passthrough pairs
    unsigned cp[32];
    #pragma unroll
    for (int kp = 0; kp < 6; ++kp) {
        u16v c0, c1, c2;
        sload3((const unsigned*)&g_lstm[kp * 48], c0, c1, c2);
        h2 h;
        lstm_one(c0, c1, c2, 0, x[2 * kp], h);
        cp[2 * kp] = as_u32(h);
        if (kp < 5) {
            lstm_one(c0, c1, c2, 24, x[2 * kp + 1], h);
            cp[2 * kp + 1] = as_u32(h);
        }
    }
    #pragma unroll
    for (int t = 0; t < 6; ++t) cp[11 + t] = as_u32(pk(x[11 + t].x, x[11 + t].y));
    #pragma unroll
    for (int t = 17; t < 32; ++t) cp[t] = 0u;            // zero K-tail (NaN-safe)

    // stage0: write own full row (row = l), sequential pairs, swizzled
    {
        const int m = (l & 7) << 2;
        #pragma unroll
        for (int ch = 0; ch < 8; ++ch) {
            uint4 q = make_uint4(cp[4*ch], cp[4*ch+1], cp[4*ch+2], cp[4*ch+3]);
            *(uint4*)&my[l * 32 + ((4 * ch) ^ m)] = q;
        }
    }

    h8 a[4][2];
    f4 acc[4][4];

    read_afrags(a, my, l);
    layer_mfma<4, 0, 0>(a, acc, bs, l);      // L1: 34 -> 51
    spill_act<4>(acc, my, l);

    read_afrags(a, my, l);
    layer_mfma<4, 8, 4>(a, acc, bs, l);      // L2: 51 -> 51
    spill_act<4>(acc, my, l);

    read_afrags(a, my, l);
    layer_mfma<3, 16, 8>(a, acc, bs, l);     // L3: 51 -> 34
    spill_act<3>(acc, my, l);

    read_afrags(a, my, l);
    layer_mfma<1, 22, 11>(a, acc, bs, l);    // L4: 34 -> 5

    // stage PRE-sigmoid f32 into own (now dead) act region, 9-padded
    {
        const int c = l & 15, g = l >> 4;
        float* po = (float*)my;
        if (c < 5) {
            #pragma unroll
            for (int mt = 0; mt < 4; ++mt)
              #pragma unroll
              for (int r = 0; r < 4; ++r)
                po[(mt * 16 + g * 4 + r) * 9 + c] = acc[mt][0][r];
        }
    }
    __syncthreads();

    // block-wide coalesced store: sigmoid applied here (5 trans/thread,
    // full lane utilization, no divergence)
    const long long ob = rb * 5;
    const float* pact = (const float*)act;
    #pragma unroll
    for (int it = 0; it < 5; ++it) {
        int F   = it * BLK + tid;
        int row = (F * 52429) >> 18;                     // F / 5, exact for F < 2^15
        int cc  = F - row * 5;
        out[ob + F] = sig1(pact[(row >> 6) * 2048 + (row & 63) * 9 + cc]);
    }
}

extern "C" void kernel_launch(void* const* d_in, const int* in_sizes, int n_in,
                              void* d_out, int out_size, void* d_ws, size_t ws_size,
                              hipStream_t stream)
{
    const float* input = (const float*)d_in[0];
    const float* W_ih  = (const float*)d_in[1];
    const float* b_ih  = (const float*)d_in[2];
    const float* b_hh  = (const float*)d_in[3];
    const float* W1    = (const float*)d_in[4];
    const float* b1    = (const float*)d_in[5];
    const float* W2    = (const float*)d_in[6];
    const float* b2    = (const float*)d_in[7];
    const float* W3    = (const float*)d_in[8];
    const float* b3    = (const float*)d_in[9];
    const float* W4    = (const float*)d_in[10];
    const float* b4    = (const float*)d_in[11];
    float* out = (float*)d_out;

    int nrows = in_sizes[0] / 34;
    int grid  = nrows / BLK;

    hipLaunchKernelGGL(prep_weights, dim3(8), dim3(256), 0, stream,
                       W_ih, b_ih, b_hh, W1, b1, W2, b2, W3, b3, W4, b4);
    hipLaunchKernelGGL(fused_rnn_mlp, dim3(grid), dim3(BLK), 0, stream,
                       input, out, nrows);
}

// Round 14
// 60.130 us; speedup vs baseline: 1.2446x; 1.0001x over previous
//
#include <hip/hip_runtime.h>

// Fused LSTM-heads + 4-layer MLP on the MATRIX pipe.  (r10 structure)
// 256-thread block = 4 independent wave-slices; each wave owns 64 rows + an
// 8KB LDS activation tile. Spill uses lane-local K-permuted pairing with
// ADJACENT positions (2c -> cols (c,16+c), 2c+1 -> cols (32+c,48+c)) so each
// (mt,r) is ONE ds_write_b64; L2/L3/L4 B-fragments pre-packed to the induced
// position->k map. relu via v_pk_max_f16 after packing (exact).
// r13: fused-rcp sig*tanh; epilogue sigmoid in the block-wide store loop.
// r14: bias rides the ks=0 MFMA C operand DIRECTLY (per-layer bias4[nt]
//      fragment, built once) -- removes ~190 v_mov acc-inits per wave.

#define BLK  256
#define WPB  4
#define KSEQ 11

typedef _Float16 h2   __attribute__((ext_vector_type(2)));
typedef _Float16 h8   __attribute__((ext_vector_type(8)));
typedef float    f4   __attribute__((ext_vector_type(4)));
typedef unsigned u16v __attribute__((ext_vector_type(16)));

#define N_FRAG_U32 6144   // 24 tiles * 64 lanes * 4 u32 (f16 pairs)
#define N_BIAS     768    // 12 bias-tiles * 64 lanes (f32 bits)
#define N_LSTM     288    // 12 * 24 floats (W_ih 16 + folded bias 8 per k)

__device__ __align__(16) float    g_lstm[N_LSTM];
__device__ __align__(16) unsigned g_frag[N_FRAG_U32];
__device__ __align__(16) unsigned g_bias[N_BIAS];

__device__ __forceinline__ h2 pk(float a, float b) {
    auto r = __builtin_amdgcn_cvt_pkrtz(a, b);
    union { decltype(r) f; h2 h; } c; c.f = r; return c.h;
}
__device__ __forceinline__ unsigned as_u32(h2 h) {
    union { h2 h; unsigned u; } c; c.h = h; return c.u;
}
__device__ __forceinline__ float uf(unsigned u) {
    union { unsigned u; float f; } c; c.u = u; return c.f;
}
__device__ __forceinline__ unsigned pkrelu(float a, float b) {   // pack then v_pk_max_f16
    h2 p = pk(a, b);
    h2 z = {(_Float16)0.0f, (_Float16)0.0f};
    h2 r = __builtin_elementwise_max(p, z);
    return as_u32(r);
}
__device__ __forceinline__ float fast_exp(float x) {
#if __has_builtin(__builtin_amdgcn_exp2f)
    return __builtin_amdgcn_exp2f(x * 1.44269504088896340736f);
#else
    return __expf(x);
#endif
}
__device__ __forceinline__ float fast_rcp(float x) {
#if __has_builtin(__builtin_amdgcn_rcpf)
    return __builtin_amdgcn_rcpf(x);
#else
    return 1.0f / x;
#endif
}
__device__ __forceinline__ float sig1(float x)  { return fast_rcp(1.0f + fast_exp(-x)); }

// sig(a) * tanh(b) with a single rcp:
// = (e^{2b} - 1) / [ (1 + e^{-a}) * (e^{2b} + 1) ]
__device__ __forceinline__ float sigtanh(float a, float b) {
    float ea = fast_exp(-a);
    float eb = fast_exp(2.0f * b);
    return (eb - 1.0f) * fast_rcp((1.0f + ea) * (eb + 1.0f));
}

// scalar-pipe load of 48 u32 (LSTM params for a k-pair); waitcnt fused in-block
__device__ __forceinline__ void sload3(const unsigned* p, u16v& c0, u16v& c1, u16v& c2) {
    asm volatile("s_load_dwordx16 %0, %3, 0x0\n\t"
                 "s_load_dwordx16 %1, %3, 0x40\n\t"
                 "s_load_dwordx16 %2, %3, 0x80\n\t"
                 "s_waitcnt lgkmcnt(0)"
                 : "=&s"(c0), "=&s"(c1), "=&s"(c2) : "s"(p));
}
__device__ __forceinline__ unsigned pick48(const u16v& c0, const u16v& c1, const u16v& c2, int j) {
    return j < 16 ? c0[j] : (j < 32 ? c1[j - 16] : c2[j - 32]);
}

__device__ __forceinline__ void lstm_one(const u16v& c0, const u16v& c1, const u16v& c2, int base,
                                         float2 x, h2& outp)
{
    float w0  = uf(pick48(c0, c1, c2, base + 0)),  w1  = uf(pick48(c0, c1, c2, base + 1));
    float w2  = uf(pick48(c0, c1, c2, base + 2)),  w3  = uf(pick48(c0, c1, c2, base + 3));
    float w8  = uf(pick48(c0, c1, c2, base + 8)),  w9  = uf(pick48(c0, c1, c2, base + 9));
    float w10 = uf(pick48(c0, c1, c2, base + 10)), w11 = uf(pick48(c0, c1, c2, base + 11));
    float w12 = uf(pick48(c0, c1, c2, base + 12)), w13 = uf(pick48(c0, c1, c2, base + 13));
    float w14 = uf(pick48(c0, c1, c2, base + 14)), w15 = uf(pick48(c0, c1, c2, base + 15));
    float B0  = uf(pick48(c0, c1, c2, base + 16)), B1v = uf(pick48(c0, c1, c2, base + 17));
    float B4  = uf(pick48(c0, c1, c2, base + 20)), B5  = uf(pick48(c0, c1, c2, base + 21));
    float B6  = uf(pick48(c0, c1, c2, base + 22)), B7  = uf(pick48(c0, c1, c2, base + 23));

    float x0 = x.x, x1 = x.y;
    float gi0 = B0  + x0 * w0  + x1 * w1;
    float gi1 = B1v + x0 * w2  + x1 * w3;
    float gg0 = B4  + x0 * w8  + x1 * w9;
    float gg1 = B5  + x0 * w10 + x1 * w11;
    float go0 = B6  + x0 * w12 + x1 * w13;
    float go1 = B7  + x0 * w14 + x1 * w15;
    float cc0 = sigtanh(gi0, gg0);
    float cc1 = sigtanh(gi1, gg1);
    float h0  = sigtanh(go0, cc0);
    float h1  = sigtanh(go1, cc1);
    outp = pk(h0, h1);
}

// ---- prep: pack B-fragments, bias tiles, LSTM params ----
// tile ids: L1: 0..7 = ks*4+nt | L2: 8..15 | L3: 16..21 = 16+ks*3+nt | L4: 22..23
// Position->k map (u32 position p within a 32-position activation row):
//   L1 input (stage0, sequential): position p holds k-pair (2p, 2p+1)
//   L2/L3/L4 input (b64 spill):    p even -> (p/2, 16+p/2), p odd -> (32+p/2, 48+p/2)
// B element (lane,j) reads position p = ks*16 + (lane>>4)*4 + j.
__global__ void prep_weights(const float* __restrict__ W_ih, const float* __restrict__ b_ih,
                             const float* __restrict__ b_hh,
                             const float* __restrict__ W1, const float* __restrict__ b1,
                             const float* __restrict__ W2, const float* __restrict__ b2,
                             const float* __restrict__ W3, const float* __restrict__ b3,
                             const float* __restrict__ W4, const float* __restrict__ b4)
{
    const int gid = blockIdx.x * blockDim.x + threadIdx.x;
    const int gs  = gridDim.x * blockDim.x;

    for (int i = gid; i < N_FRAG_U32; i += gs) {
        int t = i >> 8, rlo = i & 255;
        int lane = rlo >> 2, j = rlo & 3;
        const float* W; int N, K, ld, ks, nt;
        if (t < 8)       { W = W1; N = 51; K = 34; ld = 34; ks = t >> 2;     nt = t & 3; }
        else if (t < 16) { W = W2; N = 51; K = 51; ld = 51; ks = (t-8) >> 2; nt = (t-8) & 3; }
        else if (t < 22) { W = W3; N = 34; K = 51; ld = 51; ks = (t-16) / 3; nt = (t-16) % 3; }
        else             { W = W4; N = 5;  K = 34; ld = 34; ks = t - 22;     nt = 0; }
        int n = nt * 16 + (lane & 15);
        int p = ks * 16 + (lane >> 4) * 4 + j;
        int k_lo, k_hi;
        if (t < 8) { k_lo = 2 * p;                              k_hi = k_lo + 1;  }
        else       { k_lo = (p & 1) ? 32 + (p >> 1) : (p >> 1); k_hi = k_lo + 16; }
        float a = (n < N && k_lo < K) ? W[n * ld + k_lo] : 0.f;
        float b = (n < N && k_hi < K) ? W[n * ld + k_hi] : 0.f;
        g_frag[i] = as_u32(pk(a, b));
    }
    for (int i = gid; i < N_BIAS; i += gs) {
        int bt = i >> 6, lane = i & 63;
        const float* bv; int N, nt;
        if (bt < 4)       { bv = b1; N = 51; nt = bt; }
        else if (bt < 8)  { bv = b2; N = 51; nt = bt - 4; }
        else if (bt < 11) { bv = b3; N = 34; nt = bt - 8; }
        else              { bv = b4; N = 5;  nt = 0; }
        int col = nt * 16 + (lane & 15);
        g_bias[i] = __float_as_uint(col < N ? bv[col] : 0.f);
    }
    for (int i = gid; i < N_LSTM; i += gs) {
        int k = i / 24, cc = i - k * 24;
        float v = 0.f;
        if (k < KSEQ) v = (cc < 16) ? W_ih[k * 16 + cc]
                                    : b_ih[k * 8 + (cc - 16)] + b_hh[k * 8 + (cc - 16)];
        g_lstm[i] = v;
    }
}

// ---- main kernel helpers ----
__device__ __forceinline__ h8 load_frag(int tile, int l) {
    union { uint4 u; h8 h; } u;
    u.u = *(const uint4*)&g_frag[tile * 256 + l * 4];
    return u.h;
}

__device__ __forceinline__ void read_afrags(h8 (&a)[4][2], const unsigned* my, int l)
{
    const int c = l & 15, g = l >> 4;
    const int mrd = (c & 7) << 2;                        // swizzle mask, row = c
    #pragma unroll
    for (int mt = 0; mt < 4; ++mt)
      #pragma unroll
      for (int ks = 0; ks < 2; ++ks) {
        int idx = (mt * 16 + c) * 32 + ((ks * 16 + g * 4) ^ mrd);
        union { uint4 u; h8 h; } u;
        u.u = *(const uint4*)&my[idx];
        a[mt][ks] = u.h;
      }
}

// r14: ks=0 MFMA consumes the bias fragment DIRECTLY as its C operand
// (bias4[nt] built once per layer; C is a read-only input, D != C is legal).
// Bit-identical to init-then-accumulate, minus ~190 v_mov per wave.
template<int NT, int TBASE, int BBASE>
__device__ __forceinline__ void layer_mfma(const h8 (&a)[4][2], f4 (&acc)[4][4],
                                           const float (&bs)[12], int l)
{
    f4 bias4[NT];
    #pragma unroll
    for (int nt = 0; nt < NT; ++nt) {
        float b = bs[BBASE + nt];
        bias4[nt] = f4{b, b, b, b};
    }
    #pragma unroll
    for (int nt = 0; nt < NT; ++nt) {                    // ks = 0: C = bias
        h8 bf = load_frag(TBASE + nt, l);
        #pragma unroll
        for (int mt = 0; mt < 4; ++mt)
          acc[mt][nt] = __builtin_amdgcn_mfma_f32_16x16x32_f16(a[mt][0], bf, bias4[nt], 0, 0, 0);
    }
    #pragma unroll
    for (int nt = 0; nt < NT; ++nt) {                    // ks = 1: accumulate
        h8 bf = load_frag(TBASE + NT + nt, l);
        #pragma unroll
        for (int mt = 0; mt < 4; ++mt)
          acc[mt][nt] = __builtin_amdgcn_mfma_f32_16x16x32_f16(a[mt][1], bf, acc[mt][nt], 0, 0, 0);
    }
}

// pack + v_pk_max_f16 relu; ONE ds_write_b64 per (mt,r):
// position 2c holds cols (c, 16+c), position 2c+1 holds cols (32+c, 48+c).
// Swizzle mask has bits >=2 only, so (2c)^rowm stays 8B-aligned.
template<int NT>
__device__ __forceinline__ void spill_act(const f4 (&acc)[4][4], unsigned* my, int l)
{
    const int g = l >> 4, c = l & 15;
    #pragma unroll
    for (int mt = 0; mt < 4; ++mt)
      #pragma unroll
      for (int r = 0; r < 4; ++r) {
        const int row  = mt * 16 + g * 4 + r;
        const int rowm = (row & 7) << 2;
        uint2 q;
        q.x = pkrelu(acc[mt][0][r], acc[mt][1][r]);
        float d3 = (NT >= 4) ? acc[mt][3][r] : 0.f;
        q.y = pkrelu(acc[mt][2][r], d3);
        *(uint2*)&my[row * 32 + ((2 * c) ^ rowm)] = q;
      }
}

__global__ __launch_bounds__(BLK, 3)
void fused_rnn_mlp(const float* __restrict__ in, float* __restrict__ out, int nrows)
{
    __shared__ unsigned act[WPB * 2048];                 // 8 KB per wave-slice
    const int tid = threadIdx.x;
    const int w = tid >> 6, l = tid & 63;
    unsigned* my = &act[w * 2048];
    const long long rb = (long long)blockIdx.x * BLK;
    if (rb + BLK > nrows) return;
    const long long rw = rb + w * 64;

    // bias tiles (12 coalesced dwords)
    float bs[12];
    #pragma unroll
    for (int i = 0; i < 12; ++i) bs[i] = uf(g_bias[i * 64 + l]);

    // own row (8B-aligned, 136B stride)
    float2 x[17];
    {
        const float2* rp = (const float2*)(in + (rw + l) * 34);
        #pragma unroll
        for (int i = 0; i < 17; ++i) x[i] = rp[i];
    }

    // LSTM heads (scalar-pipe params) -> 11 h-pairs + 6 passthrough pairs
    unsigned cp[32];
    #pragma unroll
    for (int kp = 0; kp < 6; ++kp) {
        u16v c0, c1, c2;
        sload3((const unsigned*)&g_lstm[kp * 48], c0, c1, c2);
        h2 h;
        lstm_one(c0, c1, c2, 0, x[2 * kp], h);
        cp[2 * kp] = as_u32(h);
        if (kp < 5) {
            lstm_one(c0, c1, c2, 24, x[2 * kp + 1], h);
            cp[2 * kp + 1] = as_u32(h);
        }
    }
    #pragma unroll
    for (int t = 0; t < 6; ++t) cp[11 + t] = as_u32(pk(x[11 + t].x, x[11 + t].y));
    #pragma unroll
    for (int t = 17; t < 32; ++t) cp[t] = 0u;            // zero K-tail (NaN-safe)

    // stage0: write own full row (row = l), sequential pairs, swizzled
    {
        const int m = (l & 7) << 2;
        #pragma unroll
        for (int ch = 0; ch < 8; ++ch) {
            uint4 q = make_uint4(cp[4*ch], cp[4*ch+1], cp[4*ch+2], cp[4*ch+3]);
            *(uint4*)&my[l * 32 + ((4 * ch) ^ m)] = q;
        }
    }

    h8 a[4][2];
    f4 acc[4][4];

    read_afrags(a, my, l);
    layer_mfma<4, 0, 0>(a, acc, bs, l);      // L1: 34 -> 51
    spill_act<4>(acc, my, l);

    read_afrags(a, my, l);
    layer_mfma<4, 8, 4>(a, acc, bs, l);      // L2: 51 -> 51
    spill_act<4>(acc, my, l);

    read_afrags(a, my, l);
    layer_mfma<3, 16, 8>(a, acc, bs, l);     // L3: 51 -> 34
    spill_act<3>(acc, my, l);

    read_afrags(a, my, l);
    layer_mfma<1, 22, 11>(a, acc, bs, l);    // L4: 34 -> 5

    // stage PRE-sigmoid f32 into own (now dead) act region, 9-padded
    {
        const int c = l & 15, g = l >> 4;
        float* po = (float*)my;
        if (c < 5) {
            #pragma unroll
            for (int mt = 0; mt < 4; ++mt)
              #pragma unroll
              for (int r = 0; r < 4; ++r)
                po[(mt * 16 + g * 4 + r) * 9 + c] = acc[mt][0][r];
        }
    }
    __syncthreads();

    // block-wide coalesced store: sigmoid applied here (5 trans/thread,
    // full lane utilization, no divergence)
    const long long ob = rb * 5;
    const float* pact = (const float*)act;
    #pragma unroll
    for (int it = 0; it < 5; ++it) {
        int F   = it * BLK + tid;
        int row = (F * 52429) >> 18;                     // F / 5, exact for F < 2^15
        int cc  = F - row * 5;
        out[ob + F] = sig1(pact[(row >> 6) * 2048 + (row & 63) * 9 + cc]);
    }
}

extern "C" void kernel_launch(void* const* d_in, const int* in_sizes, int n_in,
                              void* d_out, int out_size, void* d_ws, size_t ws_size,
                              hipStream_t stream)
{
    const float* input = (const float*)d_in[0];
    const float* W_ih  = (const float*)d_in[1];
    const float* b_ih  = (const float*)d_in[2];
    const float* b_hh  = (const float*)d_in[3];
    const float* W1    = (const float*)d_in[4];
    const float* b1    = (const float*)d_in[5];
    const float* W2    = (const float*)d_in[6];
    const float* b2    = (const float*)d_in[7];
    const float* W3    = (const float*)d_in[8];
    const float* b3    = (const float*)d_in[9];
    const float* W4    = (const float*)d_in[10];
    const float* b4    = (const float*)d_in[11];
    float* out = (float*)d_out;

    int nrows = in_sizes[0] / 34;
    int grid  = nrows / BLK;

    hipLaunchKernelGGL(prep_weights, dim3(8), dim3(256), 0, stream,
                       W_ih, b_ih, b_hh, W1, b1, W2, b2, W3, b3, W4, b4);
    hipLaunchKernelGGL(fused_rnn_mlp, dim3(grid), dim3(BLK), 0, stream,
                       input, out, nrows);
}